// Round 2
// baseline (632.799 us; speedup 1.0000x reference)
//
#include <hip/hip_runtime.h>
#include <hip/hip_bf16.h>

// QuantizedLinear: out[M,N] = (x[M,K] @ W^T) * scale + bias, W[N,K] = q - zp
// M = 8192, N = 4096, K = 4096.
// R1: conversions rewritten as grid-stride, unit-stride-per-instruction,
// 2x unrolled (they were 1.35 TB/s; target ~6 TB/s). GEMM unchanged (696 TF).

typedef __bf16 bf16x8 __attribute__((ext_vector_type(8)));
typedef float  f32x4  __attribute__((ext_vector_type(4)));

#define BM 128
#define BN 128
#define BK 32

// ---------------- conversion kernels ----------------
// x: fp32 -> bf16. Grid-stride over float4s; lane-adjacent = address-adjacent
// within every load/store instruction. uint2 (8B) stores.

__global__ __launch_bounds__(256) void cvt_x_bf16(
    const float4* __restrict__ x, uint2* __restrict__ o, int n4) {
  int t = blockIdx.x * 256 + threadIdx.x;
  int T = gridDim.x * 256;
  int i = t;
  // 2x unrolled main loop: two independent loads in flight per iteration.
  for (; i + T < n4; i += 2 * T) {
    float4 a = x[i];
    float4 b = x[i + T];
    union { __bf16 h[4]; uint2 u; } ra, rb;
    ra.h[0] = (__bf16)a.x; ra.h[1] = (__bf16)a.y;
    ra.h[2] = (__bf16)a.z; ra.h[3] = (__bf16)a.w;
    rb.h[0] = (__bf16)b.x; rb.h[1] = (__bf16)b.y;
    rb.h[2] = (__bf16)b.z; rb.h[3] = (__bf16)b.w;
    o[i] = ra.u;
    o[i + T] = rb.u;
  }
  for (; i < n4; i += T) {
    float4 a = x[i];
    union { __bf16 h[4]; uint2 u; } ra;
    ra.h[0] = (__bf16)a.x; ra.h[1] = (__bf16)a.y;
    ra.h[2] = (__bf16)a.z; ra.h[3] = (__bf16)a.w;
    o[i] = ra.u;
  }
}

// w: int32 -> bf16 of (q - zp). Exact (|q-zp| < 256, bf16 has 8 mantissa bits).
__global__ __launch_bounds__(256) void cvt_w_bf16(
    const int4* __restrict__ q, const int* __restrict__ zp,
    uint2* __restrict__ o, int n4) {
  int t = blockIdx.x * 256 + threadIdx.x;
  int T = gridDim.x * 256;
  int z = zp[0];
  int i = t;
  for (; i + T < n4; i += 2 * T) {
    int4 a = q[i];
    int4 b = q[i + T];
    union { __bf16 h[4]; uint2 u; } ra, rb;
    ra.h[0] = (__bf16)(float)(a.x - z); ra.h[1] = (__bf16)(float)(a.y - z);
    ra.h[2] = (__bf16)(float)(a.z - z); ra.h[3] = (__bf16)(float)(a.w - z);
    rb.h[0] = (__bf16)(float)(b.x - z); rb.h[1] = (__bf16)(float)(b.y - z);
    rb.h[2] = (__bf16)(float)(b.z - z); rb.h[3] = (__bf16)(float)(b.w - z);
    o[i] = ra.u;
    o[i + T] = rb.u;
  }
  for (; i < n4; i += T) {
    int4 a = q[i];
    union { __bf16 h[4]; uint2 u; } ra;
    ra.h[0] = (__bf16)(float)(a.x - z); ra.h[1] = (__bf16)(float)(a.y - z);
    ra.h[2] = (__bf16)(float)(a.z - z); ra.h[3] = (__bf16)(float)(a.w - z);
    o[i] = ra.u;
  }
}

// ---------------- GEMM (m97 structure, unchanged from R0) ----------------

__global__ __launch_bounds__(256) void gemm_bt(
    const __bf16* __restrict__ A, const __bf16* __restrict__ Bw,
    const float* __restrict__ scale, const float* __restrict__ bias,
    float* __restrict__ C, int M, int N, int K) {
  __shared__ __bf16 As[BM * BK];
  __shared__ __bf16 Bs[BN * BK];

  const int tid  = threadIdx.x;
  const int wave = tid >> 6;
  const int lane = tid & 63;

  const int m0 = blockIdx.y * BM;
  const int n0 = blockIdx.x * BN;

  const int s_row = lane >> 2;          // 0..15
  const int s_col = (lane & 3) * 8;     // 0,8,16,24

  const __bf16* Ag = A  + (size_t)(m0 + wave * 32 + s_row) * K + s_col;
  const __bf16* Bg = Bw + (size_t)(n0 + wave * 32 + s_row) * K + s_col;
  __bf16* Asl = As + (wave * 32) * BK;
  __bf16* Bsl = Bs + (wave * 32) * BK;

  const int wm   = (wave >> 1) * 64;
  const int wn   = (wave & 1) * 64;
  const int fr   = lane & 15;
  const int quad = lane >> 4;

  f32x4 acc[4][4] = {};

  for (int k0 = 0; k0 < K; k0 += BK) {
    __builtin_amdgcn_global_load_lds(
        (const __attribute__((address_space(1))) void*)(Ag + k0),
        (__attribute__((address_space(3))) void*)(Asl), 16, 0, 0);
    __builtin_amdgcn_global_load_lds(
        (const __attribute__((address_space(1))) void*)(Ag + (size_t)16 * K + k0),
        (__attribute__((address_space(3))) void*)(Asl + 16 * BK), 16, 0, 0);
    __builtin_amdgcn_global_load_lds(
        (const __attribute__((address_space(1))) void*)(Bg + k0),
        (__attribute__((address_space(3))) void*)(Bsl), 16, 0, 0);
    __builtin_amdgcn_global_load_lds(
        (const __attribute__((address_space(1))) void*)(Bg + (size_t)16 * K + k0),
        (__attribute__((address_space(3))) void*)(Bsl + 16 * BK), 16, 0, 0);
    __syncthreads();

    bf16x8 af[4], bfr[4];
#pragma unroll
    for (int i = 0; i < 4; i++)
      af[i] = *(const bf16x8*)(As + (wm + i * 16 + fr) * BK + quad * 8);
#pragma unroll
    for (int j = 0; j < 4; j++)
      bfr[j] = *(const bf16x8*)(Bs + (wn + j * 16 + fr) * BK + quad * 8);

#pragma unroll
    for (int i = 0; i < 4; i++)
#pragma unroll
      for (int j = 0; j < 4; j++)
        acc[i][j] = __builtin_amdgcn_mfma_f32_16x16x32_bf16(
            af[i], bfr[j], acc[i][j], 0, 0, 0);
    __syncthreads();
  }

  const float s = scale[0];
#pragma unroll
  for (int i = 0; i < 4; i++) {
    const int row = m0 + wm + i * 16 + quad * 4;
#pragma unroll
    for (int j = 0; j < 4; j++) {
      const int col = n0 + wn + j * 16 + fr;
      const float bv = bias[col];
      float* cp = C + (size_t)row * N + col;
#pragma unroll
      for (int r = 0; r < 4; r++)
        cp[(size_t)r * N] = s * acc[i][j][r] + bv;
    }
  }
}

// ---------------- launch ----------------

extern "C" void kernel_launch(void* const* d_in, const int* in_sizes, int n_in,
                              void* d_out, int out_size, void* d_ws, size_t ws_size,
                              hipStream_t stream) {
  const int M = 8192, N = 4096, K = 4096;

  const float* x    = (const float*)d_in[0];
  const int*   qw   = (const int*)d_in[1];
  const int*   zp   = (const int*)d_in[2];
  const float* sc   = (const float*)d_in[3];
  const float* bias = (const float*)d_in[4];
  float* out = (float*)d_out;

  __bf16* x_bf = (__bf16*)d_ws;
  __bf16* w_bf = (__bf16*)((char*)d_ws + (size_t)M * K * sizeof(__bf16));

  {
    int n4 = (M * K) / 4;  // 8,388,608 float4s
    cvt_x_bf16<<<2048, 256, 0, stream>>>((const float4*)x, (uint2*)x_bf, n4);
  }
  {
    int n4 = (N * K) / 4;  // 4,194,304 int4s
    cvt_w_bf16<<<2048, 256, 0, stream>>>((const int4*)qw, zp, (uint2*)w_bf, n4);
  }

  dim3 grid(N / BN, M / BM);  // (32, 64)
  gemm_bt<<<grid, 256, 0, stream>>>(x_bf, w_bf, sc, bias, out, M, N, K);
}